// Round 4
// baseline (294.171 us; speedup 1.0000x reference)
//
#include <hip/hip_runtime.h>

#define F 128

// ---- 1. degree counts (int atomics) ----
__global__ __launch_bounds__(256)
void deg_kernel(const int* __restrict__ src, const int* __restrict__ dst,
                int* __restrict__ cnt_out, int* __restrict__ cnt_in, int E) {
    int e = blockIdx.x * blockDim.x + threadIdx.x;
    if (e < E) {
        atomicAdd(&cnt_out[src[e]], 1);
        atomicAdd(&cnt_in[dst[e]], 1);
    }
}

// ---- 2a. per-block (1024-elem) sums of cnt_in ----
__global__ __launch_bounds__(256)
void scan_p1(const int* __restrict__ cnt, int* __restrict__ bsum, int N) {
    int b = blockIdx.x, t = threadIdx.x;
    int i0 = b * 1024 + t * 4;
    int s = 0;
    #pragma unroll
    for (int j = 0; j < 4; ++j) { int i = i0 + j; if (i < N) s += cnt[i]; }
    #pragma unroll
    for (int off = 32; off > 0; off >>= 1) s += __shfl_down(s, off);
    __shared__ int ws[4];
    int lane = t & 63, w = t >> 6;
    if (lane == 0) ws[w] = s;
    __syncthreads();
    if (t == 0) bsum[b] = ws[0] + ws[1] + ws[2] + ws[3];
}

// ---- 2b. exclusive scan of block sums (single wave; NB <= 64) ----
__global__ __launch_bounds__(64)
void scan_p2(const int* __restrict__ bsum, int* __restrict__ boff,
             int* __restrict__ row_off, int NB, int N, int E) {
    int t = threadIdx.x;
    int v = (t < NB) ? bsum[t] : 0;
    int incl = v;
    #pragma unroll
    for (int off = 1; off < 64; off <<= 1) {
        int u = __shfl_up(incl, off);
        if (t >= off) incl += u;
    }
    if (t < NB) boff[t] = incl - v;
    if (t == 0) row_off[N] = E;   // sum of in-degrees == E
}

// ---- 2c. block-local scan -> row_off + cursor; fused inv_out = rsqrt(deg_out) ----
// cnt_out_cursor: read as deg_out, then overwritten as CSR cursor (same thread,
// read-before-write, same address -> safe).
__global__ __launch_bounds__(256)
void scan_p3(const int* __restrict__ cnt_in, const int* __restrict__ boff,
             int* __restrict__ row_off, int* cnt_out_cursor,
             float* __restrict__ inv_out, int N) {
    int b = blockIdx.x, t = threadIdx.x;
    int i0 = b * 1024 + t * 4;
    int v[4]; int s = 0;
    #pragma unroll
    for (int j = 0; j < 4; ++j) { int i = i0 + j; v[j] = (i < N) ? cnt_in[i] : 0; s += v[j]; }
    int lane = t & 63, w = t >> 6;
    int incl = s;
    #pragma unroll
    for (int off = 1; off < 64; off <<= 1) {
        int u = __shfl_up(incl, off);
        if (lane >= off) incl += u;
    }
    __shared__ int wsum[4];
    if (lane == 63) wsum[w] = incl;
    __syncthreads();
    int wbase = 0;
    #pragma unroll
    for (int j = 0; j < 4; ++j) if (j < w) wbase += wsum[j];
    int run = boff[b] + wbase + (incl - s);
    #pragma unroll
    for (int j = 0; j < 4; ++j) {
        int i = i0 + j;
        if (i < N) {
            int co = cnt_out_cursor[i];
            inv_out[i] = rsqrtf(fmaxf((float)co, 1.0f));
            row_off[i] = run;
            cnt_out_cursor[i] = run;     // cursor init
            run += v[j];
        }
    }
}

// ---- 3. bucket edges into CSR ----
__global__ __launch_bounds__(256)
void fill_kernel(const int* __restrict__ src, const int* __restrict__ dst,
                 int* __restrict__ cursor, int* __restrict__ csr_src, int E) {
    int e = blockIdx.x * blockDim.x + threadIdx.x;
    if (e < E) {
        int pos = atomicAdd(&cursor[dst[e]], 1);
        csr_src[pos] = src[e];
    }
}

// ---- 4. GEMM first: Y = (x @ W) * inv_out[row]   (scale commutes with @W) ----
__global__ __launch_bounds__(256)
void gemm_kernel(const float* __restrict__ x, const float* __restrict__ W,
                 const float* __restrict__ inv_out, float* __restrict__ Y, int N) {
    __shared__ float Ws[32 * 128];
    __shared__ float Hs[32 * 36];
    const int t = threadIdx.x;
    const int r0 = blockIdx.x * 32;
    const int tc = t & 31;
    const int tr = t >> 5;

    float4 a0 = {0,0,0,0}, a1 = {0,0,0,0}, a2 = {0,0,0,0}, a3 = {0,0,0,0};

    for (int kc = 0; kc < 4; ++kc) {
        const int k0 = kc * 32;
        #pragma unroll
        for (int j = 0; j < 16; ++j) {
            int i = t + 256 * j;
            int kk = i >> 7, c = i & 127;
            Ws[kk * 128 + c] = W[(k0 + kk) * F + c];
        }
        #pragma unroll
        for (int j = 0; j < 4; ++j) {
            int i = t + 256 * j;
            int r = i >> 5, kk = i & 31;
            int row = min(r0 + r, N - 1);
            Hs[kk * 36 + r] = x[(long long)row * F + k0 + kk];
        }
        __syncthreads();
        #pragma unroll
        for (int kk = 0; kk < 32; ++kk) {
            float4 hv = *(const float4*)&Hs[kk * 36 + 4 * tr];
            float4 wv = *(const float4*)&Ws[kk * 128 + 4 * tc];
            a0.x = fmaf(hv.x, wv.x, a0.x); a0.y = fmaf(hv.x, wv.y, a0.y);
            a0.z = fmaf(hv.x, wv.z, a0.z); a0.w = fmaf(hv.x, wv.w, a0.w);
            a1.x = fmaf(hv.y, wv.x, a1.x); a1.y = fmaf(hv.y, wv.y, a1.y);
            a1.z = fmaf(hv.y, wv.z, a1.z); a1.w = fmaf(hv.y, wv.w, a1.w);
            a2.x = fmaf(hv.z, wv.x, a2.x); a2.y = fmaf(hv.z, wv.y, a2.y);
            a2.z = fmaf(hv.z, wv.z, a2.z); a2.w = fmaf(hv.z, wv.w, a2.w);
            a3.x = fmaf(hv.w, wv.x, a3.x); a3.y = fmaf(hv.w, wv.y, a3.y);
            a3.z = fmaf(hv.w, wv.z, a3.z); a3.w = fmaf(hv.w, wv.w, a3.w);
        }
        __syncthreads();
    }

    float4 acc[4] = {a0, a1, a2, a3};
    #pragma unroll
    for (int i = 0; i < 4; ++i) {
        int row = r0 + 4 * tr + i;
        if (row < N) {
            float sc = inv_out[row];
            float4 o = acc[i];
            o.x *= sc; o.y *= sc; o.z *= sc; o.w *= sc;
            *(float4*)&Y[(long long)row * F + 4 * tc] = o;
        }
    }
}

// ---- 5. gather: one wave per node; half-waves take even/odd CSR slots,
//         32 lanes x float4 = one 128-feat row per half-wave per step ----
__global__ __launch_bounds__(256)
void gather_kernel(const float* __restrict__ Y, const int* __restrict__ csr_src,
                   const int* __restrict__ row_off, const float* __restrict__ bias,
                   float* __restrict__ out, int N) {
    int v = blockIdx.x * 4 + (threadIdx.x >> 6);
    if (v >= N) return;
    int lane = threadIdx.x & 63;
    int half = lane >> 5;
    int l32  = lane & 31;
    int beg = row_off[v], end = row_off[v + 1];
    float4 a0 = {0,0,0,0}, a1 = {0,0,0,0};
    int j = beg + half;
    for (; j + 2 < end; j += 4) {
        int s0 = csr_src[j];
        int s1 = csr_src[j + 2];
        float4 v0 = *(const float4*)(Y + (long long)s0 * F + l32 * 4);
        float4 v1 = *(const float4*)(Y + (long long)s1 * F + l32 * 4);
        a0.x += v0.x; a0.y += v0.y; a0.z += v0.z; a0.w += v0.w;
        a1.x += v1.x; a1.y += v1.y; a1.z += v1.z; a1.w += v1.w;
    }
    if (j < end) {
        int s0 = csr_src[j];
        float4 v0 = *(const float4*)(Y + (long long)s0 * F + l32 * 4);
        a0.x += v0.x; a0.y += v0.y; a0.z += v0.z; a0.w += v0.w;
    }
    a0.x += a1.x; a0.y += a1.y; a0.z += a1.z; a0.w += a1.w;
    // combine the two half-waves
    a0.x += __shfl_xor(a0.x, 32);
    a0.y += __shfl_xor(a0.y, 32);
    a0.z += __shfl_xor(a0.z, 32);
    a0.w += __shfl_xor(a0.w, 32);
    if (half == 0) {
        float invd = rsqrtf(fmaxf((float)(end - beg), 1.0f));
        float4 b = *(const float4*)(bias + l32 * 4);
        float4 o;
        o.x = a0.x * invd + b.x;
        o.y = a0.y * invd + b.y;
        o.z = a0.z * invd + b.z;
        o.w = a0.w * invd + b.w;
        *(float4*)(out + (long long)v * F + l32 * 4) = o;
    }
}

extern "C" void kernel_launch(void* const* d_in, const int* in_sizes, int n_in,
                              void* d_out, int out_size, void* d_ws, size_t ws_size,
                              hipStream_t stream) {
    const float* x    = (const float*)d_in[0];
    const int*   src  = (const int*)d_in[1];
    const int*   dst  = (const int*)d_in[2];
    const float* W    = (const float*)d_in[3];
    const float* bias = (const float*)d_in[4];
    float* out = (float*)d_out;

    const int N = in_sizes[0] / F;     // 50000
    const int E = in_sizes[1];         // 800000
    const int NB = (N + 1023) / 1024;  // scan blocks

    // workspace layout (4-byte elems)
    int*   cnt_out = (int*)d_ws;            // [N] -> cursor after scan_p3
    int*   cnt_in  = cnt_out + N;           // [N]
    int*   row_off = cnt_in + N;            // [N+1]
    int*   csr_src = row_off + N + 1;       // [E]
    float* inv_out = (float*)(csr_src + E); // [N]
    int*   bsum    = (int*)(inv_out + N);   // [NB]
    int*   boff    = bsum + NB;             // [NB]
    float* Y       = (float*)(boff + NB);   // [N*F]

    hipMemsetAsync(d_ws, 0, (size_t)2 * N * sizeof(int), stream);

    deg_kernel<<<(E + 255) / 256, 256, 0, stream>>>(src, dst, cnt_out, cnt_in, E);
    scan_p1<<<NB, 256, 0, stream>>>(cnt_in, bsum, N);
    scan_p2<<<1, 64, 0, stream>>>(bsum, boff, row_off, NB, N, E);
    scan_p3<<<NB, 256, 0, stream>>>(cnt_in, boff, row_off, cnt_out, inv_out, N);
    int* cursor = cnt_out;
    fill_kernel<<<(E + 255) / 256, 256, 0, stream>>>(src, dst, cursor, csr_src, E);
    gemm_kernel<<<(N + 31) / 32, 256, 0, stream>>>(x, W, inv_out, Y, N);
    gather_kernel<<<(N + 3) / 4, 256, 0, stream>>>(Y, csr_src, row_off, bias, out, N);
}

// Round 5
// 282.642 us; speedup vs baseline: 1.0408x; 1.0408x over previous
//
#include <hip/hip_runtime.h>

#define F 128
#define RANGE 12500   // nodes per LDS-histogram range (50 KB LDS, 3 blocks/CU)

// ---- 1. per-(range,slice) LDS histogram of idx[] values; no global atomics ----
__global__ __launch_bounds__(256)
void hist_kernel(const int* __restrict__ idx, int* __restrict__ part,
                 int E, int S, int SLICE, int N) {
    __shared__ int lh[RANGE];
    int b = blockIdx.x, t = threadIdx.x;
    int r = b / S, s = b % S;
    int lo = r * RANGE;
    for (int i = t; i < RANGE; i += 256) lh[i] = 0;
    __syncthreads();
    int e0 = s * SLICE, e1 = min(e0 + SLICE, E);
    for (int e = e0 + t; e < e1; e += 256) {
        int v = idx[e] - lo;
        if ((unsigned)v < (unsigned)RANGE) atomicAdd(&lh[v], 1);
    }
    __syncthreads();
    int* outp = part + (size_t)b * RANGE;
    for (int i = t; i < RANGE; i += 256) outp[i] = lh[i];
}

// ---- 2a. out-degree: sum partials -> inv_out = rsqrt(max(deg,1)) ----
__global__ __launch_bounds__(256)
void reduce_src_kernel(const int* __restrict__ part, float* __restrict__ inv_out,
                       int S, int N) {
    int v = blockIdx.x * 256 + threadIdx.x;
    if (v >= N) return;
    int r = v / RANGE, vp = v % RANGE;
    const int* p = part + (size_t)r * S * RANGE + vp;
    int sum = 0;
    for (int s = 0; s < S; ++s) sum += p[(size_t)s * RANGE];
    inv_out[v] = rsqrtf(fmaxf((float)sum, 1.0f));
}

// ---- 2b. in-degree: sum + in-place exclusive prefix over slices ----
__global__ __launch_bounds__(256)
void reduce_dst_kernel(int* __restrict__ part, int* __restrict__ cnt_in,
                       int S, int N) {
    int v = blockIdx.x * 256 + threadIdx.x;
    if (v >= N) return;
    int r = v / RANGE, vp = v % RANGE;
    int* p = part + (size_t)r * S * RANGE + vp;
    int run = 0;
    for (int s = 0; s < S; ++s) {
        int tval = p[(size_t)s * RANGE];
        p[(size_t)s * RANGE] = run;
        run += tval;
    }
    cnt_in[v] = run;
}

// ---- 3a. per-block (1024-elem) sums of cnt_in ----
__global__ __launch_bounds__(256)
void scan_p1(const int* __restrict__ cnt, int* __restrict__ bsum, int N) {
    int b = blockIdx.x, t = threadIdx.x;
    int i0 = b * 1024 + t * 4;
    int s = 0;
    #pragma unroll
    for (int j = 0; j < 4; ++j) { int i = i0 + j; if (i < N) s += cnt[i]; }
    #pragma unroll
    for (int off = 32; off > 0; off >>= 1) s += __shfl_down(s, off);
    __shared__ int ws[4];
    int lane = t & 63, w = t >> 6;
    if (lane == 0) ws[w] = s;
    __syncthreads();
    if (t == 0) bsum[b] = ws[0] + ws[1] + ws[2] + ws[3];
}

// ---- 3b. exclusive scan of block sums (single wave; NB <= 64) ----
__global__ __launch_bounds__(64)
void scan_p2(const int* __restrict__ bsum, int* __restrict__ boff,
             int* __restrict__ row_off, int NB, int N, int E) {
    int t = threadIdx.x;
    int v = (t < NB) ? bsum[t] : 0;
    int incl = v;
    #pragma unroll
    for (int off = 1; off < 64; off <<= 1) {
        int u = __shfl_up(incl, off);
        if (t >= off) incl += u;
    }
    if (t < NB) boff[t] = incl - v;
    if (t == 0) row_off[N] = E;   // sum of in-degrees == E
}

// ---- 3c. block-local scan -> row_off ----
__global__ __launch_bounds__(256)
void scan_p3(const int* __restrict__ cnt_in, const int* __restrict__ boff,
             int* __restrict__ row_off, int N) {
    int b = blockIdx.x, t = threadIdx.x;
    int i0 = b * 1024 + t * 4;
    int v[4]; int s = 0;
    #pragma unroll
    for (int j = 0; j < 4; ++j) { int i = i0 + j; v[j] = (i < N) ? cnt_in[i] : 0; s += v[j]; }
    int lane = t & 63, w = t >> 6;
    int incl = s;
    #pragma unroll
    for (int off = 1; off < 64; off <<= 1) {
        int u = __shfl_up(incl, off);
        if (lane >= off) incl += u;
    }
    __shared__ int wsum[4];
    if (lane == 63) wsum[w] = incl;
    __syncthreads();
    int wbase = 0;
    #pragma unroll
    for (int j = 0; j < 4; ++j) if (j < w) wbase += wsum[j];
    int run = boff[b] + wbase + (incl - s);
    #pragma unroll
    for (int j = 0; j < 4; ++j) {
        int i = i0 + j;
        if (i < N) { row_off[i] = run; run += v[j]; }
    }
}

// ---- 4. CSR fill with LDS cursors (no global atomics) ----
// cursor base = row_off[v] + exclusive-prefix-over-slices (stored in part)
__global__ __launch_bounds__(256)
void fill_kernel(const int* __restrict__ src, const int* __restrict__ dst,
                 const int* __restrict__ row_off, const int* __restrict__ part,
                 int* __restrict__ csr_src, int E, int S, int SLICE, int N) {
    __shared__ int cur[RANGE];
    int b = blockIdx.x, t = threadIdx.x;
    int r = b / S, s = b % S;
    int lo = r * RANGE;
    int hi = min(lo + RANGE, N);
    const int* pp = part + (size_t)b * RANGE;
    for (int i = t; i < hi - lo; i += 256) cur[i] = row_off[lo + i] + pp[i];
    __syncthreads();
    int e0 = s * SLICE, e1 = min(e0 + SLICE, E);
    for (int e = e0 + t; e < e1; e += 256) {
        int d = dst[e] - lo;
        if ((unsigned)d < (unsigned)(hi - lo)) {
            int pos = atomicAdd(&cur[d], 1);       // LDS atomic
            csr_src[pos] = src[e];                 // plain store
        }
    }
}

// ---- 5. GEMM first: Y = (x @ W) * inv_out[row]   (scale commutes with @W) ----
__global__ __launch_bounds__(256)
void gemm_kernel(const float* __restrict__ x, const float* __restrict__ W,
                 const float* __restrict__ inv_out, float* __restrict__ Y, int N) {
    __shared__ float Ws[32 * 128];
    __shared__ float Hs[32 * 36];
    const int t = threadIdx.x;
    const int r0 = blockIdx.x * 32;
    const int tc = t & 31;
    const int tr = t >> 5;

    float4 a0 = {0,0,0,0}, a1 = {0,0,0,0}, a2 = {0,0,0,0}, a3 = {0,0,0,0};

    for (int kc = 0; kc < 4; ++kc) {
        const int k0 = kc * 32;
        #pragma unroll
        for (int j = 0; j < 16; ++j) {
            int i = t + 256 * j;
            int kk = i >> 7, c = i & 127;
            Ws[kk * 128 + c] = W[(k0 + kk) * F + c];
        }
        #pragma unroll
        for (int j = 0; j < 4; ++j) {
            int i = t + 256 * j;
            int r = i >> 5, kk = i & 31;
            int row = min(r0 + r, N - 1);
            Hs[kk * 36 + r] = x[(long long)row * F + k0 + kk];
        }
        __syncthreads();
        #pragma unroll
        for (int kk = 0; kk < 32; ++kk) {
            float4 hv = *(const float4*)&Hs[kk * 36 + 4 * tr];
            float4 wv = *(const float4*)&Ws[kk * 128 + 4 * tc];
            a0.x = fmaf(hv.x, wv.x, a0.x); a0.y = fmaf(hv.x, wv.y, a0.y);
            a0.z = fmaf(hv.x, wv.z, a0.z); a0.w = fmaf(hv.x, wv.w, a0.w);
            a1.x = fmaf(hv.y, wv.x, a1.x); a1.y = fmaf(hv.y, wv.y, a1.y);
            a1.z = fmaf(hv.y, wv.z, a1.z); a1.w = fmaf(hv.y, wv.w, a1.w);
            a2.x = fmaf(hv.z, wv.x, a2.x); a2.y = fmaf(hv.z, wv.y, a2.y);
            a2.z = fmaf(hv.z, wv.z, a2.z); a2.w = fmaf(hv.z, wv.w, a2.w);
            a3.x = fmaf(hv.w, wv.x, a3.x); a3.y = fmaf(hv.w, wv.y, a3.y);
            a3.z = fmaf(hv.w, wv.z, a3.z); a3.w = fmaf(hv.w, wv.w, a3.w);
        }
        __syncthreads();
    }

    float4 acc[4] = {a0, a1, a2, a3};
    #pragma unroll
    for (int i = 0; i < 4; ++i) {
        int row = r0 + 4 * tr + i;
        if (row < N) {
            float sc = inv_out[row];
            float4 o = acc[i];
            o.x *= sc; o.y *= sc; o.z *= sc; o.w *= sc;
            *(float4*)&Y[(long long)row * F + 4 * tc] = o;
        }
    }
}

// ---- 6. gather: one wave per node; half-waves take even/odd CSR slots ----
__global__ __launch_bounds__(256)
void gather_kernel(const float* __restrict__ Y, const int* __restrict__ csr_src,
                   const int* __restrict__ row_off, const float* __restrict__ bias,
                   float* __restrict__ out, int N) {
    int v = blockIdx.x * 4 + (threadIdx.x >> 6);
    if (v >= N) return;
    int lane = threadIdx.x & 63;
    int half = lane >> 5;
    int l32  = lane & 31;
    int beg = row_off[v], end = row_off[v + 1];
    float4 a0 = {0,0,0,0}, a1 = {0,0,0,0};
    int j = beg + half;
    for (; j + 2 < end; j += 4) {
        int s0 = csr_src[j];
        int s1 = csr_src[j + 2];
        float4 v0 = *(const float4*)(Y + (long long)s0 * F + l32 * 4);
        float4 v1 = *(const float4*)(Y + (long long)s1 * F + l32 * 4);
        a0.x += v0.x; a0.y += v0.y; a0.z += v0.z; a0.w += v0.w;
        a1.x += v1.x; a1.y += v1.y; a1.z += v1.z; a1.w += v1.w;
    }
    if (j < end) {
        int s0 = csr_src[j];
        float4 v0 = *(const float4*)(Y + (long long)s0 * F + l32 * 4);
        a0.x += v0.x; a0.y += v0.y; a0.z += v0.z; a0.w += v0.w;
    }
    a0.x += a1.x; a0.y += a1.y; a0.z += a1.z; a0.w += a1.w;
    a0.x += __shfl_xor(a0.x, 32);
    a0.y += __shfl_xor(a0.y, 32);
    a0.z += __shfl_xor(a0.z, 32);
    a0.w += __shfl_xor(a0.w, 32);
    if (half == 0) {
        float invd = rsqrtf(fmaxf((float)(end - beg), 1.0f));
        float4 b = *(const float4*)(bias + l32 * 4);
        float4 o;
        o.x = a0.x * invd + b.x;
        o.y = a0.y * invd + b.y;
        o.z = a0.z * invd + b.z;
        o.w = a0.w * invd + b.w;
        *(float4*)(out + (long long)v * F + l32 * 4) = o;
    }
}

extern "C" void kernel_launch(void* const* d_in, const int* in_sizes, int n_in,
                              void* d_out, int out_size, void* d_ws, size_t ws_size,
                              hipStream_t stream) {
    const float* x    = (const float*)d_in[0];
    const int*   src  = (const int*)d_in[1];
    const int*   dst  = (const int*)d_in[2];
    const float* W    = (const float*)d_in[3];
    const float* bias = (const float*)d_in[4];
    float* out = (float*)d_out;

    const int N = in_sizes[0] / F;        // 50000
    const int E = in_sizes[1];            // 800000
    const int NB = (N + 1023) / 1024;     // scan blocks (<= 64 required by p2)
    const int R = (N + RANGE - 1) / RANGE; // node ranges (4)

    // pick slice count S so the workspace fits
    size_t fixed_words = (size_t)N        // cnt_in
                       + (size_t)(N + 1)  // row_off
                       + (size_t)N        // inv_out
                       + (size_t)2 * NB   // bsum, boff
                       + (size_t)E        // csr_src
                       + (size_t)N * F;   // Y
    int S = 64;
    while (S > 2 && (fixed_words + (size_t)R * S * RANGE) * 4 > ws_size) S >>= 1;
    const int SLICE = (E + S - 1) / S;

    // workspace layout (4-byte elems)
    int*   part    = (int*)d_ws;            // [R*S*RANGE] (src pass, then dst pass)
    int*   cnt_in  = part + (size_t)R * S * RANGE;
    int*   row_off = cnt_in + N;            // [N+1]
    float* inv_out = (float*)(row_off + N + 1);
    int*   bsum    = (int*)(inv_out + N);   // [NB]
    int*   boff    = bsum + NB;             // [NB]
    int*   csr_src = boff + NB;             // [E]
    float* Y       = (float*)(csr_src + E); // [N*F]

    const int hgrid = R * S;
    const int ngrid = (N + 255) / 256;

    // out-degrees -> inv_out
    hist_kernel<<<hgrid, 256, 0, stream>>>(src, part, E, S, SLICE, N);
    reduce_src_kernel<<<ngrid, 256, 0, stream>>>(part, inv_out, S, N);
    // in-degrees -> cnt_in, per-slice prefix kept in part
    hist_kernel<<<hgrid, 256, 0, stream>>>(dst, part, E, S, SLICE, N);
    reduce_dst_kernel<<<ngrid, 256, 0, stream>>>(part, cnt_in, S, N);
    // row offsets
    scan_p1<<<NB, 256, 0, stream>>>(cnt_in, bsum, N);
    scan_p2<<<1, 64, 0, stream>>>(bsum, boff, row_off, NB, N, E);
    scan_p3<<<NB, 256, 0, stream>>>(cnt_in, boff, row_off, N);
    // CSR fill (LDS cursors)
    fill_kernel<<<hgrid, 256, 0, stream>>>(src, dst, row_off, part, csr_src, E, S, SLICE, N);
    // dense phase
    gemm_kernel<<<(N + 31) / 32, 256, 0, stream>>>(x, W, inv_out, Y, N);
    gather_kernel<<<(N + 3) / 4, 256, 0, stream>>>(Y, csr_src, row_off, bias, out, N);
}

// Round 6
// 256.831 us; speedup vs baseline: 1.1454x; 1.1005x over previous
//
#include <hip/hip_runtime.h>

#define F 128
#define RANGE 12500   // nodes per LDS-histogram range (50 KB LDS)

typedef unsigned short ushort_t;

__device__ inline float bf_lo(unsigned u) { return __uint_as_float(u << 16); }
__device__ inline float bf_hi(unsigned u) { return __uint_as_float(u & 0xffff0000u); }
__device__ inline ushort_t f2bf(float f) {          // RNE float->bf16
    unsigned u = __float_as_uint(f);
    return (ushort_t)((u + 0x7fff + ((u >> 16) & 1)) >> 16);
}

// ---- 1. per-(range,slice) LDS histogram; no global atomics ----
__global__ __launch_bounds__(256)
void hist_kernel(const int* __restrict__ idx, int* __restrict__ part,
                 int E, int S, int SLICE, int N) {
    __shared__ int lh[RANGE];
    int b = blockIdx.x, t = threadIdx.x;
    int r = b / S, s = b % S;
    int lo = r * RANGE;
    for (int i = t; i < RANGE; i += 256) lh[i] = 0;
    __syncthreads();
    int e0 = s * SLICE, e1 = min(e0 + SLICE, E);
    for (int e = e0 + t; e < e1; e += 256) {
        int v = idx[e] - lo;
        if ((unsigned)v < (unsigned)RANGE) atomicAdd(&lh[v], 1);
    }
    __syncthreads();
    int* outp = part + (size_t)b * RANGE;
    for (int i = t; i < RANGE; i += 256) outp[i] = lh[i];
}

// ---- 2a. out-degree: sum partials -> inv_out = rsqrt(max(deg,1)) ----
__global__ __launch_bounds__(256)
void reduce_src_kernel(const int* __restrict__ part, float* __restrict__ inv_out,
                       int S, int N) {
    int v = blockIdx.x * 256 + threadIdx.x;
    if (v >= N) return;
    int r = v / RANGE, vp = v % RANGE;
    const int* p = part + (size_t)r * S * RANGE + vp;
    int sum = 0;
    for (int s = 0; s < S; ++s) sum += p[(size_t)s * RANGE];
    inv_out[v] = rsqrtf(fmaxf((float)sum, 1.0f));
}

// ---- 2b. in-degree: sum + in-place exclusive prefix over slices ----
__global__ __launch_bounds__(256)
void reduce_dst_kernel(int* __restrict__ part, int* __restrict__ cnt_in,
                       int S, int N) {
    int v = blockIdx.x * 256 + threadIdx.x;
    if (v >= N) return;
    int r = v / RANGE, vp = v % RANGE;
    int* p = part + (size_t)r * S * RANGE + vp;
    int run = 0;
    for (int s = 0; s < S; ++s) {
        int tval = p[(size_t)s * RANGE];
        p[(size_t)s * RANGE] = run;
        run += tval;
    }
    cnt_in[v] = run;
}

// ---- 3a. per-block (1024-elem) sums of cnt_in ----
__global__ __launch_bounds__(256)
void scan_p1(const int* __restrict__ cnt, int* __restrict__ bsum, int N) {
    int b = blockIdx.x, t = threadIdx.x;
    int i0 = b * 1024 + t * 4;
    int s = 0;
    #pragma unroll
    for (int j = 0; j < 4; ++j) { int i = i0 + j; if (i < N) s += cnt[i]; }
    #pragma unroll
    for (int off = 32; off > 0; off >>= 1) s += __shfl_down(s, off);
    __shared__ int ws[4];
    int lane = t & 63, w = t >> 6;
    if (lane == 0) ws[w] = s;
    __syncthreads();
    if (t == 0) bsum[b] = ws[0] + ws[1] + ws[2] + ws[3];
}

// ---- 3b. exclusive scan of block sums (single wave; NB <= 64) ----
__global__ __launch_bounds__(64)
void scan_p2(const int* __restrict__ bsum, int* __restrict__ boff,
             int* __restrict__ row_off, int NB, int N, int E) {
    int t = threadIdx.x;
    int v = (t < NB) ? bsum[t] : 0;
    int incl = v;
    #pragma unroll
    for (int off = 1; off < 64; off <<= 1) {
        int u = __shfl_up(incl, off);
        if (t >= off) incl += u;
    }
    if (t < NB) boff[t] = incl - v;
    if (t == 0) row_off[N] = E;
}

// ---- 3c. block-local scan -> row_off ----
__global__ __launch_bounds__(256)
void scan_p3(const int* __restrict__ cnt_in, const int* __restrict__ boff,
             int* __restrict__ row_off, int N) {
    int b = blockIdx.x, t = threadIdx.x;
    int i0 = b * 1024 + t * 4;
    int v[4]; int s = 0;
    #pragma unroll
    for (int j = 0; j < 4; ++j) { int i = i0 + j; v[j] = (i < N) ? cnt_in[i] : 0; s += v[j]; }
    int lane = t & 63, w = t >> 6;
    int incl = s;
    #pragma unroll
    for (int off = 1; off < 64; off <<= 1) {
        int u = __shfl_up(incl, off);
        if (lane >= off) incl += u;
    }
    __shared__ int wsum[4];
    if (lane == 63) wsum[w] = incl;
    __syncthreads();
    int wbase = 0;
    #pragma unroll
    for (int j = 0; j < 4; ++j) if (j < w) wbase += wsum[j];
    int run = boff[b] + wbase + (incl - s);
    #pragma unroll
    for (int j = 0; j < 4; ++j) {
        int i = i0 + j;
        if (i < N) { row_off[i] = run; run += v[j]; }
    }
}

// ---- 4. CSR fill with LDS cursors (no global atomics) ----
__global__ __launch_bounds__(256)
void fill_kernel(const int* __restrict__ src, const int* __restrict__ dst,
                 const int* __restrict__ row_off, const int* __restrict__ part,
                 int* __restrict__ csr_src, int E, int S, int SLICE, int N) {
    __shared__ int cur[RANGE];
    int b = blockIdx.x, t = threadIdx.x;
    int r = b / S, s = b % S;
    int lo = r * RANGE;
    int hi = min(lo + RANGE, N);
    const int* pp = part + (size_t)b * RANGE;
    for (int i = t; i < hi - lo; i += 256) cur[i] = row_off[lo + i] + pp[i];
    __syncthreads();
    int e0 = s * SLICE, e1 = min(e0 + SLICE, E);
    for (int e = e0 + t; e < e1; e += 256) {
        int d = dst[e] - lo;
        if ((unsigned)d < (unsigned)(hi - lo)) {
            int pos = atomicAdd(&cur[d], 1);       // LDS atomic
            csr_src[pos] = src[e];                 // plain store
        }
    }
}

// ---- 5. GEMM: Y = bf16( (x @ W) * inv_out[row] ) ----
__global__ __launch_bounds__(256)
void gemm_kernel(const float* __restrict__ x, const float* __restrict__ W,
                 const float* __restrict__ inv_out, ushort_t* __restrict__ Y, int N) {
    __shared__ float Ws[32 * 128];
    __shared__ float Hs[32 * 36];
    const int t = threadIdx.x;
    const int r0 = blockIdx.x * 32;
    const int tc = t & 31;
    const int tr = t >> 5;

    float4 a0 = {0,0,0,0}, a1 = {0,0,0,0}, a2 = {0,0,0,0}, a3 = {0,0,0,0};

    for (int kc = 0; kc < 4; ++kc) {
        const int k0 = kc * 32;
        #pragma unroll
        for (int j = 0; j < 16; ++j) {
            int i = t + 256 * j;
            int kk = i >> 7, c = i & 127;
            Ws[kk * 128 + c] = W[(k0 + kk) * F + c];
        }
        #pragma unroll
        for (int j = 0; j < 4; ++j) {
            int i = t + 256 * j;
            int r = i >> 5, kk = i & 31;
            int row = min(r0 + r, N - 1);
            Hs[kk * 36 + r] = x[(long long)row * F + k0 + kk];
        }
        __syncthreads();
        #pragma unroll
        for (int kk = 0; kk < 32; ++kk) {
            float4 hv = *(const float4*)&Hs[kk * 36 + 4 * tr];
            float4 wv = *(const float4*)&Ws[kk * 128 + 4 * tc];
            a0.x = fmaf(hv.x, wv.x, a0.x); a0.y = fmaf(hv.x, wv.y, a0.y);
            a0.z = fmaf(hv.x, wv.z, a0.z); a0.w = fmaf(hv.x, wv.w, a0.w);
            a1.x = fmaf(hv.y, wv.x, a1.x); a1.y = fmaf(hv.y, wv.y, a1.y);
            a1.z = fmaf(hv.y, wv.z, a1.z); a1.w = fmaf(hv.y, wv.w, a1.w);
            a2.x = fmaf(hv.z, wv.x, a2.x); a2.y = fmaf(hv.z, wv.y, a2.y);
            a2.z = fmaf(hv.z, wv.z, a2.z); a2.w = fmaf(hv.z, wv.w, a2.w);
            a3.x = fmaf(hv.w, wv.x, a3.x); a3.y = fmaf(hv.w, wv.y, a3.y);
            a3.z = fmaf(hv.w, wv.z, a3.z); a3.w = fmaf(hv.w, wv.w, a3.w);
        }
        __syncthreads();
    }

    float4 acc[4] = {a0, a1, a2, a3};
    #pragma unroll
    for (int i = 0; i < 4; ++i) {
        int row = r0 + 4 * tr + i;
        if (row < N) {
            float sc = inv_out[row];
            float4 o = acc[i];
            ushort4 yv;
            yv.x = f2bf(o.x * sc);
            yv.y = f2bf(o.y * sc);
            yv.z = f2bf(o.z * sc);
            yv.w = f2bf(o.w * sc);
            *(ushort4*)&Y[(long long)row * F + 4 * tc] = yv;
        }
    }
}

// ---- 6. gather: wave per node; quarter-waves (16 lanes x uint4 = 8 bf16)
//         take CSR slots j = beg+q, stride 4, unroll x2 ----
__global__ __launch_bounds__(256)
void gather_kernel(const ushort_t* __restrict__ Y, const int* __restrict__ csr_src,
                   const int* __restrict__ row_off, const float* __restrict__ bias,
                   float* __restrict__ out, int N) {
    int v = blockIdx.x * 4 + (threadIdx.x >> 6);
    if (v >= N) return;
    int lane = threadIdx.x & 63;
    int q = lane >> 4;        // quarter 0..3
    int l16 = lane & 15;      // feats 8*l16 .. 8*l16+7
    int beg = row_off[v], end = row_off[v + 1];
    float accA[8] = {0,0,0,0,0,0,0,0};
    float accB[8] = {0,0,0,0,0,0,0,0};
    int j = beg + q;
    for (; j + 4 < end; j += 8) {
        int s0 = csr_src[j];
        int s1 = csr_src[j + 4];
        uint4 u0 = *(const uint4*)(Y + (size_t)s0 * F + l16 * 8);
        uint4 u1 = *(const uint4*)(Y + (size_t)s1 * F + l16 * 8);
        accA[0] += bf_lo(u0.x); accA[1] += bf_hi(u0.x);
        accA[2] += bf_lo(u0.y); accA[3] += bf_hi(u0.y);
        accA[4] += bf_lo(u0.z); accA[5] += bf_hi(u0.z);
        accA[6] += bf_lo(u0.w); accA[7] += bf_hi(u0.w);
        accB[0] += bf_lo(u1.x); accB[1] += bf_hi(u1.x);
        accB[2] += bf_lo(u1.y); accB[3] += bf_hi(u1.y);
        accB[4] += bf_lo(u1.z); accB[5] += bf_hi(u1.z);
        accB[6] += bf_lo(u1.w); accB[7] += bf_hi(u1.w);
    }
    if (j < end) {
        int s0 = csr_src[j];
        uint4 u0 = *(const uint4*)(Y + (size_t)s0 * F + l16 * 8);
        accA[0] += bf_lo(u0.x); accA[1] += bf_hi(u0.x);
        accA[2] += bf_lo(u0.y); accA[3] += bf_hi(u0.y);
        accA[4] += bf_lo(u0.z); accA[5] += bf_hi(u0.z);
        accA[6] += bf_lo(u0.w); accA[7] += bf_hi(u0.w);
    }
    #pragma unroll
    for (int i = 0; i < 8; ++i) {
        float a = accA[i] + accB[i];
        a += __shfl_xor(a, 16);
        a += __shfl_xor(a, 32);
        accA[i] = a;
    }
    if (q == 0) {
        float invd = rsqrtf(fmaxf((float)(end - beg), 1.0f));
        float4 b0 = *(const float4*)(bias + l16 * 8);
        float4 b1 = *(const float4*)(bias + l16 * 8 + 4);
        float4 o0, o1;
        o0.x = accA[0] * invd + b0.x; o0.y = accA[1] * invd + b0.y;
        o0.z = accA[2] * invd + b0.z; o0.w = accA[3] * invd + b0.w;
        o1.x = accA[4] * invd + b1.x; o1.y = accA[5] * invd + b1.y;
        o1.z = accA[6] * invd + b1.z; o1.w = accA[7] * invd + b1.w;
        *(float4*)(out + (long long)v * F + l16 * 8) = o0;
        *(float4*)(out + (long long)v * F + l16 * 8 + 4) = o1;
    }
}

extern "C" void kernel_launch(void* const* d_in, const int* in_sizes, int n_in,
                              void* d_out, int out_size, void* d_ws, size_t ws_size,
                              hipStream_t stream) {
    const float* x    = (const float*)d_in[0];
    const int*   src  = (const int*)d_in[1];
    const int*   dst  = (const int*)d_in[2];
    const float* W    = (const float*)d_in[3];
    const float* bias = (const float*)d_in[4];
    float* out = (float*)d_out;

    const int N = in_sizes[0] / F;        // 50000
    const int E = in_sizes[1];            // 800000
    const int NB = (N + 1023) / 1024;
    const int R = (N + RANGE - 1) / RANGE;

    size_t fixed_words = (size_t)N + (size_t)(N + 1) + (size_t)N
                       + (size_t)2 * NB + (size_t)E
                       + ((size_t)N * F + 1) / 2;   // Y now bf16
    int S = 64;
    while (S > 2 && (fixed_words + (size_t)R * S * RANGE) * 4 > ws_size) S >>= 1;
    const int SLICE = (E + S - 1) / S;

    int*     part    = (int*)d_ws;
    int*     cnt_in  = part + (size_t)R * S * RANGE;
    int*     row_off = cnt_in + N;
    float*   inv_out = (float*)(row_off + N + 1);
    int*     bsum    = (int*)(inv_out + N);
    int*     boff    = bsum + NB;
    int*     csr_src = boff + NB;
    ushort_t* Y      = (ushort_t*)(csr_src + E);

    const int hgrid = R * S;
    const int ngrid = (N + 255) / 256;

    hist_kernel<<<hgrid, 256, 0, stream>>>(src, part, E, S, SLICE, N);
    reduce_src_kernel<<<ngrid, 256, 0, stream>>>(part, inv_out, S, N);
    hist_kernel<<<hgrid, 256, 0, stream>>>(dst, part, E, S, SLICE, N);
    reduce_dst_kernel<<<ngrid, 256, 0, stream>>>(part, cnt_in, S, N);
    scan_p1<<<NB, 256, 0, stream>>>(cnt_in, bsum, N);
    scan_p2<<<1, 64, 0, stream>>>(bsum, boff, row_off, NB, N, E);
    scan_p3<<<NB, 256, 0, stream>>>(cnt_in, boff, row_off, N);
    fill_kernel<<<hgrid, 256, 0, stream>>>(src, dst, row_off, part, csr_src, E, S, SLICE, N);
    gemm_kernel<<<(N + 31) / 32, 256, 0, stream>>>(x, W, inv_out, Y, N);
    gather_kernel<<<(N + 3) / 4, 256, 0, stream>>>(Y, csr_src, row_off, bias, out, N);
}